// Round 1
// baseline (690.993 us; speedup 1.0000x reference)
//
#include <hip/hip_runtime.h>
#include <hip/hip_bf16.h>
#include <math.h>

// Problem constants
#define BATCH 16
#define L1 32
#define L2 128
#define DEC 512
#define MEM 512
#define TOPN 50
#define NROWS (BATCH * L1 * L2)   // 65536 word rows
#define NBQ (BATCH * L1)          // 512 (b,q) rows

// ---------------- ws layout (floats) ----------------
// bias1      : [16*512]        off 0
// bias2      : [16*512]        off 8192
// doc_scores : [512]           off 16384
// doc_attn   : [512]           off 16896
// word_part  : [4][65536]      off 17408
// ctx_part   : [512][512]      off 279552
// total 541696 floats (~2.1 MB)
#define WS_BIAS1 0
#define WS_BIAS2 8192
#define WS_DOCSC 16384
#define WS_DOCAT 16896
#define WS_WPART 17408
#define WS_CTXP  279552

// ============ kernel 1: bias1[b,d], bias2[b,d] ============
__global__ __launch_bounds__(256) void bias_kernel(
    const float* __restrict__ dec, const float* __restrict__ topic,
    const float* __restrict__ Wd, const float* __restrict__ Wt,
    const float* __restrict__ Wd2, const float* __restrict__ Wt2,
    float* __restrict__ bias1, float* __restrict__ bias2)
{
    int idx = blockIdx.x * 256 + threadIdx.x;   // 8192
    int b = idx >> 9, d = idx & 511;
    float a1 = 0.f, a2 = 0.f;
    const float* db = dec + b * DEC;
    const float* w1 = Wd + (size_t)d * DEC;
    const float* w2 = Wd2 + (size_t)d * DEC;
#pragma unroll 4
    for (int k = 0; k < DEC; ++k) {
        float x = db[k];
        a1 = fmaf(x, w1[k], a1);
        a2 = fmaf(x, w2[k], a2);
    }
    const float* tb = topic + b * TOPN;
    const float* t1 = Wt + (size_t)d * TOPN;
    const float* t2 = Wt2 + (size_t)d * TOPN;
#pragma unroll 2
    for (int t = 0; t < TOPN; ++t) {
        float x = tb[t];
        a1 = fmaf(x, t1[t], a1);
        a2 = fmaf(x, t2[t], a2);
    }
    bias1[idx] = a1;
    bias2[idx] = a2;
}

// ============ kernel 2: doc scores (8 bq-rows per block) ============
__global__ __launch_bounds__(256) void doc_score_kernel(
    const float* __restrict__ doc_memory,   // [512][512] (bq, m)
    const float* __restrict__ Wm2,          // [512][512] (d, m)
    const float* __restrict__ Wv2,          // [512]
    const float* __restrict__ bias2,        // [16][512]
    float* __restrict__ doc_scores)         // [512]
{
    __shared__ float rows[8][DEC];
    __shared__ float red[4][8];
    const int bq0 = blockIdx.x * 8;     // 64 blocks
    const int b = bq0 >> 5;
    const int tid = threadIdx.x;

    // stage 8 rows (4096 floats = 1024 float4)
#pragma unroll
    for (int i = 0; i < 4; ++i) {
        int idx = tid + i * 256;
        int r = idx >> 7;
        int c = (idx & 127) * 4;
        *(float4*)&rows[r][c] = *(const float4*)(doc_memory + (size_t)(bq0 + r) * DEC + c);
    }
    __syncthreads();

    const int d0 = tid, d1 = tid + 256;
    float acc0[8], acc1[8];
#pragma unroll
    for (int r = 0; r < 8; ++r) { acc0[r] = 0.f; acc1[r] = 0.f; }

    const float* wr0 = Wm2 + (size_t)d0 * MEM;
    const float* wr1 = Wm2 + (size_t)d1 * MEM;
    for (int m = 0; m < MEM; m += 4) {
        float4 w0 = *(const float4*)(wr0 + m);
        float4 w1 = *(const float4*)(wr1 + m);
#pragma unroll
        for (int r = 0; r < 8; ++r) {
            float4 x = *(const float4*)&rows[r][m];
            acc0[r] = fmaf(w0.x, x.x, acc0[r]);
            acc0[r] = fmaf(w0.y, x.y, acc0[r]);
            acc0[r] = fmaf(w0.z, x.z, acc0[r]);
            acc0[r] = fmaf(w0.w, x.w, acc0[r]);
            acc1[r] = fmaf(w1.x, x.x, acc1[r]);
            acc1[r] = fmaf(w1.y, x.y, acc1[r]);
            acc1[r] = fmaf(w1.z, x.z, acc1[r]);
            acc1[r] = fmaf(w1.w, x.w, acc1[r]);
        }
    }

    float wv0 = Wv2[d0], wv1 = Wv2[d1];
    float bb0 = bias2[b * DEC + d0], bb1 = bias2[b * DEC + d1];
#pragma unroll
    for (int r = 0; r < 8; ++r) {
        float p = wv0 * tanhf(acc0[r] + bb0) + wv1 * tanhf(acc1[r] + bb1);
#pragma unroll
        for (int o = 1; o <= 32; o <<= 1) p += __shfl_xor(p, o);
        if ((tid & 63) == 0) red[tid >> 6][r] = p;
    }
    __syncthreads();
    if (tid < 8) {
        doc_scores[bq0 + tid] = red[0][tid] + red[1][tid] + red[2][tid] + red[3][tid];
    }
}

// ============ kernel 3: doc softmax ============
__global__ __launch_bounds__(512) void doc_softmax_kernel(
    const float* __restrict__ doc_scores, const int* __restrict__ doc_mask,
    float* __restrict__ doc_attn)
{
    int tid = threadIdx.x;    // 512: b = tid>>5, q = tid&31
    float s = doc_scores[tid];
    if (doc_mask[tid] == 0) s = -INFINITY;
    float mx = s;
#pragma unroll
    for (int o = 1; o <= 16; o <<= 1) mx = fmaxf(mx, __shfl_xor(mx, o));
    float e = expf(s - mx);
    float sum = e;
#pragma unroll
    for (int o = 1; o <= 16; o <<= 1) sum += __shfl_xor(sum, o);
    doc_attn[tid] = e / sum;
}

// ============ kernel 4: fused word-score GEMM ============
// scores partial over d-chunk: partial[chunk][row] = sum_{d in chunk} Wv[d]*tanh(X·Wm^T + bias1)
#define BM 128
#define BN 128
#define KC 32
__global__ __launch_bounds__(256) void word_score_kernel(
    const float* __restrict__ X,      // [65536][512]
    const float* __restrict__ Wm,     // [512][512]
    const float* __restrict__ Wv,     // [512]
    const float* __restrict__ bias1,  // [16][512]
    float* __restrict__ partial)      // [4][65536]
{
    __shared__ float Xs[KC][BM + 4];
    __shared__ float Ws[KC][BN + 4];
    const int tid = threadIdx.x;
    const int tx = tid & 15;      // d-dir (16)
    const int ty = tid >> 4;      // row-dir (16)
    const int row0 = blockIdx.x * BM;
    const int d0 = blockIdx.y * BN;
    const int b = row0 >> 12;     // 4096 rows per batch

    float acc[8][8];
#pragma unroll
    for (int i = 0; i < 8; ++i)
#pragma unroll
        for (int j = 0; j < 8; ++j) acc[i][j] = 0.f;

    const int lr = tid >> 3;            // 0..31
    const int lk = (tid & 7) << 2;      // 0,4,..,28

    for (int k0 = 0; k0 < DEC; k0 += KC) {
#pragma unroll
        for (int i = 0; i < 4; ++i) {
            int r = lr + i * 32;
            float4 v = *(const float4*)(X + (size_t)(row0 + r) * DEC + k0 + lk);
            Xs[lk + 0][r] = v.x; Xs[lk + 1][r] = v.y; Xs[lk + 2][r] = v.z; Xs[lk + 3][r] = v.w;
            float4 u = *(const float4*)(Wm + (size_t)(d0 + r) * DEC + k0 + lk);
            Ws[lk + 0][r] = u.x; Ws[lk + 1][r] = u.y; Ws[lk + 2][r] = u.z; Ws[lk + 3][r] = u.w;
        }
        __syncthreads();
#pragma unroll
        for (int k = 0; k < KC; ++k) {
            // fragment split {i, 64+i}: keeps LDS b128 reads at <=2-way bank alias (free)
            float4 a0 = *(const float4*)&Xs[k][ty * 4];
            float4 a1 = *(const float4*)&Xs[k][64 + ty * 4];
            float4 w0 = *(const float4*)&Ws[k][tx * 4];
            float4 w1 = *(const float4*)&Ws[k][64 + tx * 4];
            float a[8] = {a0.x, a0.y, a0.z, a0.w, a1.x, a1.y, a1.z, a1.w};
            float w[8] = {w0.x, w0.y, w0.z, w0.w, w1.x, w1.y, w1.z, w1.w};
#pragma unroll
            for (int i = 0; i < 8; ++i)
#pragma unroll
                for (int j = 0; j < 8; ++j)
                    acc[i][j] = fmaf(a[i], w[j], acc[i][j]);
        }
        __syncthreads();
    }

    // epilogue: tanh + Wv reduction over this block's 128 d's
    float wv[8], bs[8];
#pragma unroll
    for (int j = 0; j < 8; ++j) {
        int dl = (j < 4) ? (tx * 4 + j) : (64 + tx * 4 + (j - 4));
        int d = d0 + dl;
        wv[j] = Wv[d];
        bs[j] = bias1[b * DEC + d];
    }
#pragma unroll
    for (int i = 0; i < 8; ++i) {
        float p = 0.f;
#pragma unroll
        for (int j = 0; j < 8; ++j)
            p += wv[j] * tanhf(acc[i][j] + bs[j]);
        // reduce over the 16 tx lanes (low 4 bits of lane id)
        p += __shfl_xor(p, 1);
        p += __shfl_xor(p, 2);
        p += __shfl_xor(p, 4);
        p += __shfl_xor(p, 8);
        if (tx == 0) {
            int rl = (i < 4) ? (ty * 4 + i) : (64 + ty * 4 + (i - 4));
            partial[(size_t)blockIdx.y * NROWS + row0 + rl] = p;
        }
    }
}

// ============ kernel 5: word softmax + rescale + context partial ============
__global__ __launch_bounds__(128) void combine_kernel(
    const float* __restrict__ partial,    // [4][65536]
    const float* __restrict__ doc_attn,   // [512]
    const int* __restrict__ word_mask,    // [65536]
    const float* __restrict__ X,          // word_memory [65536][512]
    float* __restrict__ rescaled_out,     // d_out + 8192
    float* __restrict__ ctx_part)         // [512][512]
{
    __shared__ float sr[L2];
    __shared__ float rmax[2], rsum[2];
    const int bq = blockIdx.x;       // 512
    const int w = threadIdx.x;       // 128
    const int row = bq * L2 + w;

    float s = partial[row] + partial[NROWS + row] + partial[2 * NROWS + row] + partial[3 * NROWS + row];
    if (word_mask[row] == 0) s = -INFINITY;

    float mx = s;
#pragma unroll
    for (int o = 1; o <= 32; o <<= 1) mx = fmaxf(mx, __shfl_xor(mx, o));
    int wid = w >> 6;
    if ((w & 63) == 0) rmax[wid] = mx;
    __syncthreads();
    mx = fmaxf(rmax[0], rmax[1]);

    float e = expf(s - mx);
    float sum = e;
#pragma unroll
    for (int o = 1; o <= 32; o <<= 1) sum += __shfl_xor(sum, o);
    if ((w & 63) == 0) rsum[wid] = sum;
    __syncthreads();
    sum = rsum[0] + rsum[1];

    float resc = doc_attn[bq] * (e / sum);
    rescaled_out[row] = resc;
    sr[w] = resc;
    __syncthreads();

    // context partial: thread handles m = 4w..4w+3
    float4 accv = {0.f, 0.f, 0.f, 0.f};
    const float* base = X + (size_t)bq * L2 * MEM;
    const int m0 = 4 * w;
#pragma unroll 4
    for (int ww = 0; ww < L2; ++ww) {
        float r = sr[ww];
        float4 v = *(const float4*)(base + (size_t)ww * MEM + m0);
        accv.x = fmaf(r, v.x, accv.x);
        accv.y = fmaf(r, v.y, accv.y);
        accv.z = fmaf(r, v.z, accv.z);
        accv.w = fmaf(r, v.w, accv.w);
    }
    *(float4*)(ctx_part + (size_t)bq * MEM + m0) = accv;
}

// ============ kernel 6: reduce context over q ============
__global__ __launch_bounds__(256) void ctx_reduce_kernel(
    const float* __restrict__ ctx_part,   // [512][512]
    float* __restrict__ ctx_out)          // [16][512]
{
    int idx = blockIdx.x * 256 + threadIdx.x;   // 8192
    int b = idx >> 9, m = idx & 511;
    float s = 0.f;
#pragma unroll
    for (int q = 0; q < L1; ++q)
        s += ctx_part[(size_t)(b * L1 + q) * MEM + m];
    ctx_out[idx] = s;
}

extern "C" void kernel_launch(void* const* d_in, const int* in_sizes, int n_in,
                              void* d_out, int out_size, void* d_ws, size_t ws_size,
                              hipStream_t stream) {
    const float* decoder_state = (const float*)d_in[0];
    const float* doc_memory    = (const float*)d_in[1];
    const float* word_memory   = (const float*)d_in[2];
    const float* topic_dist    = (const float*)d_in[3];
    const int*   doc_mask      = (const int*)d_in[4];
    const int*   word_mask     = (const int*)d_in[5];
    const float* Wv  = (const float*)d_in[6];
    const float* Wd  = (const float*)d_in[7];
    const float* Wt  = (const float*)d_in[8];
    const float* Wm  = (const float*)d_in[9];
    const float* Wv2 = (const float*)d_in[10];
    const float* Wd2 = (const float*)d_in[11];
    const float* Wt2 = (const float*)d_in[12];
    const float* Wm2 = (const float*)d_in[13];

    float* ws = (float*)d_ws;
    float* bias1      = ws + WS_BIAS1;
    float* bias2      = ws + WS_BIAS2;
    float* doc_scores = ws + WS_DOCSC;
    float* doc_attn   = ws + WS_DOCAT;
    float* word_part  = ws + WS_WPART;
    float* ctx_part   = ws + WS_CTXP;

    float* ctx_out      = (float*)d_out;          // [16][512]
    float* rescaled_out = (float*)d_out + BATCH * MEM;  // [16][32][128]

    bias_kernel<<<32, 256, 0, stream>>>(decoder_state, topic_dist, Wd, Wt, Wd2, Wt2, bias1, bias2);
    doc_score_kernel<<<64, 256, 0, stream>>>(doc_memory, Wm2, Wv2, bias2, doc_scores);
    doc_softmax_kernel<<<1, 512, 0, stream>>>(doc_scores, doc_mask, doc_attn);
    word_score_kernel<<<dim3(NROWS / BM, DEC / BN), 256, 0, stream>>>(word_memory, Wm, Wv, bias1, word_part);
    combine_kernel<<<NBQ, 128, 0, stream>>>(word_part, doc_attn, word_mask, word_memory, rescaled_out, ctx_part);
    ctx_reduce_kernel<<<32, 256, 0, stream>>>(ctx_part, ctx_out);
}

// Round 3
// 416.708 us; speedup vs baseline: 1.6582x; 1.6582x over previous
//
#include <hip/hip_runtime.h>
#include <hip/hip_bf16.h>
#include <math.h>

// Problem constants
#define BATCH 16
#define L1 32
#define L2 128
#define DEC 512
#define MEM 512
#define TOPN 50
#define NROWS (BATCH * L1 * L2)   // 65536 word rows
#define NBQ (BATCH * L1)          // 512 (b,q) rows

typedef short short8 __attribute__((ext_vector_type(8)));
typedef float f32x16 __attribute__((ext_vector_type(16)));

// ---------------- ws layout (floats) ----------------
#define WS_WP     0          // perm bf16 Wm : 32768 slots x 16B = floats [0,131072)
#define WS_WP2    131072     // perm bf16 Wm2
#define WS_BIAS1  262144
#define WS_BIAS2  270336
#define WS_DOCSC  278528
#define WS_DOCAT  279040
#define WS_WSCORE 279552     // [65536] -> end 345088
#define WS_CTXP   0          // ctx_part [512*512] overlays Wp (dead by combine)

// packed pair via v_cvt_pk_bf16_f32
__device__ __forceinline__ unsigned int pkbf(float a, float b) {
    __hip_bfloat162 h = __float22bfloat162_rn(float2{a, b});
    union { __hip_bfloat162 h; unsigned int u; } c{h};
    return c.u;
}

__device__ __forceinline__ float fast_tanh(float x) {
    return 1.f - 2.f / (__expf(2.f * x) + 1.f);
}

// ============ kernel 0: convert+permute Wm, Wm2 to bf16 B-fragment order ============
// slot s (16B) holds Wm[d][k..k+7] as bf16, where
//   s = C*1024 + nt*64 + k8*32 + n_in ;  d = nt*32+n_in ; k = C*16 + k8*8
__global__ __launch_bounds__(256) void permute_w_kernel(
    const float* __restrict__ Wm, const float* __restrict__ Wm2,
    unsigned short* __restrict__ Wp, unsigned short* __restrict__ Wp2)
{
    int s = blockIdx.x * 256 + threadIdx.x;     // 0..32767
    int C = s >> 10;
    int u = s & 1023;
    int nt = u >> 6, k8 = (u >> 5) & 1, n_in = u & 31;
    int d = nt * 32 + n_in;
    int k = C * 16 + k8 * 8;

    const float* src = Wm + (size_t)d * DEC + k;
    uint4 v;
    v.x = pkbf(src[0], src[1]); v.y = pkbf(src[2], src[3]);
    v.z = pkbf(src[4], src[5]); v.w = pkbf(src[6], src[7]);
    ((uint4*)Wp)[s] = v;

    const float* src2 = Wm2 + (size_t)d * DEC + k;
    uint4 w;
    w.x = pkbf(src2[0], src2[1]); w.y = pkbf(src2[2], src2[3]);
    w.z = pkbf(src2[4], src2[5]); w.w = pkbf(src2[6], src2[7]);
    ((uint4*)Wp2)[s] = w;
}

// ============ kernel 1: bias1[b,d], bias2[b,d] ============
__global__ __launch_bounds__(256) void bias_kernel(
    const float* __restrict__ dec, const float* __restrict__ topic,
    const float* __restrict__ Wd, const float* __restrict__ Wt,
    const float* __restrict__ Wd2, const float* __restrict__ Wt2,
    float* __restrict__ bias1, float* __restrict__ bias2)
{
    int idx = blockIdx.x * 256 + threadIdx.x;   // 8192
    int b = idx >> 9, d = idx & 511;
    float a1 = 0.f, a2 = 0.f;
    const float* db = dec + b * DEC;
    const float* w1 = Wd + (size_t)d * DEC;
    const float* w2 = Wd2 + (size_t)d * DEC;
#pragma unroll 4
    for (int k = 0; k < DEC; ++k) {
        float x = db[k];
        a1 = fmaf(x, w1[k], a1);
        a2 = fmaf(x, w2[k], a2);
    }
    const float* tb = topic + b * TOPN;
    const float* t1 = Wt + (size_t)d * TOPN;
    const float* t2 = Wt2 + (size_t)d * TOPN;
#pragma unroll 2
    for (int t = 0; t < TOPN; ++t) {
        float x = tb[t];
        a1 = fmaf(x, t1[t], a1);
        a2 = fmaf(x, t2[t], a2);
    }
    bias1[idx] = a1;
    bias2[idx] = a2;
}

// ============ kernel 2: fused MFMA score kernel ============
// scores[row] = sum_d Wv[d] * tanh( sum_k X[row][k]*Wm[d][k] + bias[b(row)][d] )
// BM=64 rows/block, full d=512, KC=32, 256 threads (4 waves; wave w owns d in [w*128,(w+1)*128))
__global__ __launch_bounds__(256) void score_mfma_kernel(
    const float* __restrict__ X,            // [nrows][512]
    const unsigned short* __restrict__ Wp,  // permuted bf16 weights (32768 slots x 8)
    const float* __restrict__ Wv,           // [512]
    const float* __restrict__ bias,         // [16][512]
    float* __restrict__ scores,             // [nrows]
    int bshift)                             // batch = row >> bshift
{
    __shared__ __align__(16) short lsA[256 * 8];    // 4 KB : A frags (c,mt,lane,j)
    __shared__ __align__(16) short lsB[2048 * 8];   // 32 KB: B frags (c,nt,lane,j)
    __shared__ float red[4][64];

    const int tid = threadIdx.x;
    const int lane = tid & 63;
    const int wid = tid >> 6;
    const int row0 = blockIdx.x * 64;

    // ---- A staging map ----
    const int srow = tid >> 2;          // 0..63
    const int kslot = tid & 3;          // 8-k chunk within KC=32
    const int sA = ((kslot >> 1) * 2 + (srow >> 5)) * 64 + (kslot & 1) * 32 + (srow & 31);
    const float4* xs4 = (const float4*)(X + (size_t)(row0 + srow) * DEC) + kslot * 2;

    // ---- B staging: identity copy of permuted slots, manual regs->LDS ----
    // wave wid fills LDS slots [wid*512,(wid+1)*512) from global slots it*2048 + same
    const uint4* bsrc = (const uint4*)Wp + (size_t)wid * 512 + lane;

    f32x16 acc[8];   // [mt*4 + nt]
#pragma unroll
    for (int t = 0; t < 8; ++t)
        acc[t] = (f32x16){0.f,0.f,0.f,0.f, 0.f,0.f,0.f,0.f, 0.f,0.f,0.f,0.f, 0.f,0.f,0.f,0.f};

    const short8* lA = (const short8*)lsA;
    const short8* lB = (const short8*)lsB;

    for (int it = 0; it < 16; ++it) {
        // ---- B: 8 x uint4 global loads, then 8 x ds_write_b128 ----
        uint4 bv[8];
#pragma unroll
        for (int i = 0; i < 8; ++i) bv[i] = bsrc[i * 64];
        bsrc += 2048;
#pragma unroll
        for (int i = 0; i < 8; ++i)
            *((uint4*)&lsB[((size_t)wid * 512 + i * 64 + lane) * 8]) = bv[i];

        // ---- A: fp32 load + pack to bf16 ----
        float4 xv0 = xs4[0];
        float4 xv1 = xs4[1];
        xs4 += 8;
        union { unsigned int u[4]; short8 s; } xb;
        xb.u[0] = pkbf(xv0.x, xv0.y); xb.u[1] = pkbf(xv0.z, xv0.w);
        xb.u[2] = pkbf(xv1.x, xv1.y); xb.u[3] = pkbf(xv1.z, xv1.w);
        *((short8*)&lsA[sA * 8]) = xb.s;

        __syncthreads();

#pragma unroll
        for (int c = 0; c < 2; ++c) {
            short8 a0 = lA[(c * 2 + 0) * 64 + lane];
            short8 a1 = lA[(c * 2 + 1) * 64 + lane];
            short8 b0 = lB[c * 1024 + (wid * 4 + 0) * 64 + lane];
            short8 b1 = lB[c * 1024 + (wid * 4 + 1) * 64 + lane];
            short8 b2 = lB[c * 1024 + (wid * 4 + 2) * 64 + lane];
            short8 b3 = lB[c * 1024 + (wid * 4 + 3) * 64 + lane];
            acc[0] = __builtin_amdgcn_mfma_f32_32x32x16_bf16(a0, b0, acc[0], 0, 0, 0);
            acc[1] = __builtin_amdgcn_mfma_f32_32x32x16_bf16(a0, b1, acc[1], 0, 0, 0);
            acc[2] = __builtin_amdgcn_mfma_f32_32x32x16_bf16(a0, b2, acc[2], 0, 0, 0);
            acc[3] = __builtin_amdgcn_mfma_f32_32x32x16_bf16(a0, b3, acc[3], 0, 0, 0);
            acc[4] = __builtin_amdgcn_mfma_f32_32x32x16_bf16(a1, b0, acc[4], 0, 0, 0);
            acc[5] = __builtin_amdgcn_mfma_f32_32x32x16_bf16(a1, b1, acc[5], 0, 0, 0);
            acc[6] = __builtin_amdgcn_mfma_f32_32x32x16_bf16(a1, b2, acc[6], 0, 0, 0);
            acc[7] = __builtin_amdgcn_mfma_f32_32x32x16_bf16(a1, b3, acc[7], 0, 0, 0);
        }
        __syncthreads();
    }

    // ---- epilogue: tanh + Wv-reduction ----
    // C/D layout (32x32): col = lane&31 (d), row_in = (reg&3) + 8*(reg>>2) + 4*(lane>>5)
    const int col = lane & 31;
    const int h = lane >> 5;
    float wv[4], bs[2][4];
    const int b0i = (row0) >> bshift;
    const int b1i = (row0 + 32) >> bshift;
#pragma unroll
    for (int nt = 0; nt < 4; ++nt) {
        int d = wid * 128 + nt * 32 + col;
        wv[nt] = Wv[d];
        bs[0][nt] = bias[b0i * DEC + d];
        bs[1][nt] = bias[b1i * DEC + d];
    }

#pragma unroll
    for (int mt = 0; mt < 2; ++mt) {
#pragma unroll
        for (int r = 0; r < 16; ++r) {
            float p = 0.f;
#pragma unroll
            for (int nt = 0; nt < 4; ++nt) {
                float x = acc[mt * 4 + nt][r] + bs[mt][nt];
                p = fmaf(wv[nt], fast_tanh(x), p);
            }
            p += __shfl_xor(p, 16);
            p += __shfl_xor(p, 8);
            p += __shfl_xor(p, 4);
            p += __shfl_xor(p, 2);
            p += __shfl_xor(p, 1);
            if (col == mt * 16 + r) {
                int row_in = (r & 3) + 8 * (r >> 2) + 4 * h;
                red[wid][mt * 32 + row_in] = p;
            }
        }
    }
    __syncthreads();
    if (tid < 64)
        scores[row0 + tid] = red[0][tid] + red[1][tid] + red[2][tid] + red[3][tid];
}

// ============ kernel 3: doc softmax ============
__global__ __launch_bounds__(512) void doc_softmax_kernel(
    const float* __restrict__ doc_scores, const int* __restrict__ doc_mask,
    float* __restrict__ doc_attn)
{
    int tid = threadIdx.x;    // 512: b = tid>>5, q = tid&31
    float s = doc_scores[tid];
    if (doc_mask[tid] == 0) s = -INFINITY;
    float mx = s;
#pragma unroll
    for (int o = 1; o <= 16; o <<= 1) mx = fmaxf(mx, __shfl_xor(mx, o));
    float e = __expf(s - mx);
    float sum = e;
#pragma unroll
    for (int o = 1; o <= 16; o <<= 1) sum += __shfl_xor(sum, o);
    doc_attn[tid] = e / sum;
}

// ============ kernel 4: word softmax + rescale + context partial ============
__global__ __launch_bounds__(256) void combine_kernel(
    const float* __restrict__ scores,     // [65536]
    const float* __restrict__ doc_attn,   // [512]
    const int* __restrict__ word_mask,    // [65536]
    const float* __restrict__ X,          // word_memory [65536][512]
    float* __restrict__ rescaled_out,     // d_out + 8192
    float* __restrict__ ctx_part)         // [512][512]
{
    __shared__ float sr[L2];
    __shared__ float rmax[4], rsum[4];
    __shared__ float4 part[128];
    const int bq = blockIdx.x;       // 512
    const int tid = threadIdx.x;     // 256
    const int w = tid & 127;
    const int row = bq * L2 + w;

    float s = scores[row];
    if (word_mask[row] == 0) s = -INFINITY;

    float mx = s;
#pragma unroll
    for (int o = 1; o <= 32; o <<= 1) mx = fmaxf(mx, __shfl_xor(mx, o));
    int wid = tid >> 6;
    if ((tid & 63) == 0) rmax[wid] = mx;
    __syncthreads();
    mx = fmaxf(fmaxf(rmax[0], rmax[1]), fmaxf(rmax[2], rmax[3]));

    float e = __expf(s - mx);
    float sum = e;
#pragma unroll
    for (int o = 1; o <= 32; o <<= 1) sum += __shfl_xor(sum, o);
    if ((tid & 63) == 0) rsum[wid] = sum;
    __syncthreads();
    sum = (rsum[0] + rsum[1] + rsum[2] + rsum[3]) * 0.5f;  // waves duplicate halves

    float resc = doc_attn[bq] * (e / sum);
    if (tid < 128) {
        rescaled_out[row] = resc;
        sr[w] = resc;
    }
    __syncthreads();

    // context: h-half of w range, m-quad per thread
    const int hh = tid >> 7;          // 0/1
    const int m4 = tid & 127;
    const float4* xb = (const float4*)(X) + (size_t)bq * L2 * 128 + (size_t)hh * 64 * 128 + m4;
    float4 a = {0.f, 0.f, 0.f, 0.f};
#pragma unroll 8
    for (int ww = 0; ww < 64; ++ww) {
        float r = sr[hh * 64 + ww];
        float4 v = xb[(size_t)ww * 128];
        a.x = fmaf(r, v.x, a.x);
        a.y = fmaf(r, v.y, a.y);
        a.z = fmaf(r, v.z, a.z);
        a.w = fmaf(r, v.w, a.w);
    }
    if (hh == 1) part[m4] = a;
    __syncthreads();
    if (hh == 0) {
        float4 bqv = part[m4];
        a.x += bqv.x; a.y += bqv.y; a.z += bqv.z; a.w += bqv.w;
        *(float4*)(ctx_part + (size_t)bq * MEM + m4 * 4) = a;
    }
}

// ============ kernel 5: reduce context over q ============
__global__ __launch_bounds__(256) void ctx_reduce_kernel(
    const float* __restrict__ ctx_part,   // [512][512]
    float* __restrict__ ctx_out)          // [16][512]
{
    int idx = blockIdx.x * 256 + threadIdx.x;   // 8192
    int b = idx >> 9, m = idx & 511;
    float s = 0.f;
#pragma unroll
    for (int q = 0; q < L1; ++q)
        s += ctx_part[(size_t)(b * L1 + q) * MEM + m];
    ctx_out[idx] = s;
}

extern "C" void kernel_launch(void* const* d_in, const int* in_sizes, int n_in,
                              void* d_out, int out_size, void* d_ws, size_t ws_size,
                              hipStream_t stream) {
    const float* decoder_state = (const float*)d_in[0];
    const float* doc_memory    = (const float*)d_in[1];
    const float* word_memory   = (const float*)d_in[2];
    const float* topic_dist    = (const float*)d_in[3];
    const int*   doc_mask      = (const int*)d_in[4];
    const int*   word_mask     = (const int*)d_in[5];
    const float* Wv  = (const float*)d_in[6];
    const float* Wd  = (const float*)d_in[7];
    const float* Wt  = (const float*)d_in[8];
    const float* Wm  = (const float*)d_in[9];
    const float* Wv2 = (const float*)d_in[10];
    const float* Wd2 = (const float*)d_in[11];
    const float* Wt2 = (const float*)d_in[12];
    const float* Wm2 = (const float*)d_in[13];

    float* ws = (float*)d_ws;
    unsigned short* Wp  = (unsigned short*)(ws + WS_WP);
    unsigned short* Wp2 = (unsigned short*)(ws + WS_WP2);
    float* bias1       = ws + WS_BIAS1;
    float* bias2       = ws + WS_BIAS2;
    float* doc_scores  = ws + WS_DOCSC;
    float* doc_attn    = ws + WS_DOCAT;
    float* word_scores = ws + WS_WSCORE;
    float* ctx_part    = ws + WS_CTXP;   // overlays Wp/Wp2 (dead by then)

    float* ctx_out      = (float*)d_out;                 // [16][512]
    float* rescaled_out = (float*)d_out + BATCH * MEM;   // [16][32][128]

    permute_w_kernel<<<128, 256, 0, stream>>>(Wm, Wm2, Wp, Wp2);
    bias_kernel<<<32, 256, 0, stream>>>(decoder_state, topic_dist, Wd, Wt, Wd2, Wt2, bias1, bias2);
    // doc-level scores (512 rows), batch = row >> 5
    score_mfma_kernel<<<NBQ / 64, 256, 0, stream>>>(doc_memory, Wp2, Wv2, bias2, doc_scores, 5);
    doc_softmax_kernel<<<1, 512, 0, stream>>>(doc_scores, doc_mask, doc_attn);
    // word-level scores (65536 rows), batch = row >> 12
    score_mfma_kernel<<<NROWS / 64, 256, 0, stream>>>(word_memory, Wp, Wv, bias1, word_scores, 12);
    combine_kernel<<<NBQ, 256, 0, stream>>>(word_scores, doc_attn, word_mask, word_memory, rescaled_out, ctx_part);
    ctx_reduce_kernel<<<32, 256, 0, stream>>>(ctx_part, ctx_out);
}

// Round 4
// 368.295 us; speedup vs baseline: 1.8762x; 1.1315x over previous
//
#include <hip/hip_runtime.h>
#include <hip/hip_bf16.h>
#include <math.h>

// Problem constants
#define BATCH 16
#define L1 32
#define L2 128
#define DEC 512
#define MEM 512
#define TOPN 50
#define NROWS (BATCH * L1 * L2)   // 65536 word rows
#define NBQ (BATCH * L1)          // 512 (b,q) rows

typedef short short8 __attribute__((ext_vector_type(8)));
typedef float f32x16 __attribute__((ext_vector_type(16)));

// ---------------- ws layout (floats) ----------------
#define WS_WP     0          // perm bf16 Wm : 32768 slots x 16B = floats [0,131072)
#define WS_WP2    131072     // perm bf16 Wm2
#define WS_BIAS1  262144
#define WS_BIAS2  270336
#define WS_DOCSC  278528
#define WS_DOCAT  279040
#define WS_CTXP   279552     // ctx_part [512*512] -> end 541696 (~2.07 MB, same as R1)

// packed pair via v_cvt_pk_bf16_f32
__device__ __forceinline__ unsigned int pkbf(float a, float b) {
    __hip_bfloat162 h = __float22bfloat162_rn(float2{a, b});
    union { __hip_bfloat162 h; unsigned int u; } c{h};
    return c.u;
}

__device__ __forceinline__ float fast_tanh(float x) {
    return 1.f - 2.f / (__expf(2.f * x) + 1.f);
}

// ============ kernel 0 (merged setup): permute Wm/Wm2 + bias1/bias2 ============
// permute slot s (16B) holds Wm[d][k..k+7] bf16: s = C*1024 + nt*64 + k8*32 + n
//   d = nt*32+n ; k = C*16 + k8*8      (layout HW-verified in R3)
__global__ __launch_bounds__(256) void setup_kernel(
    const float* __restrict__ Wm, const float* __restrict__ Wm2,
    unsigned short* __restrict__ Wp, unsigned short* __restrict__ Wp2,
    const float* __restrict__ dec, const float* __restrict__ topic,
    const float* __restrict__ Wd, const float* __restrict__ Wt,
    const float* __restrict__ Wd2, const float* __restrict__ Wt2,
    float* __restrict__ bias1, float* __restrict__ bias2)
{
    if (blockIdx.x < 128) {
        int s = blockIdx.x * 256 + threadIdx.x;     // 0..32767
        int C = s >> 10;
        int u = s & 1023;
        int nt = u >> 6, k8 = (u >> 5) & 1, n_in = u & 31;
        int d = nt * 32 + n_in;
        int k = C * 16 + k8 * 8;

        const float* src = Wm + (size_t)d * DEC + k;
        uint4 v;
        v.x = pkbf(src[0], src[1]); v.y = pkbf(src[2], src[3]);
        v.z = pkbf(src[4], src[5]); v.w = pkbf(src[6], src[7]);
        ((uint4*)Wp)[s] = v;

        const float* src2 = Wm2 + (size_t)d * DEC + k;
        uint4 w;
        w.x = pkbf(src2[0], src2[1]); w.y = pkbf(src2[2], src2[3]);
        w.z = pkbf(src2[4], src2[5]); w.w = pkbf(src2[6], src2[7]);
        ((uint4*)Wp2)[s] = w;
    } else {
        int idx = (blockIdx.x - 128) * 256 + threadIdx.x;   // 8192
        int b = idx >> 9, d = idx & 511;
        float a1 = 0.f, a2 = 0.f;
        const float* db = dec + b * DEC;
        const float* w1 = Wd + (size_t)d * DEC;
        const float* w2 = Wd2 + (size_t)d * DEC;
#pragma unroll 4
        for (int k = 0; k < DEC; ++k) {
            float x = db[k];
            a1 = fmaf(x, w1[k], a1);
            a2 = fmaf(x, w2[k], a2);
        }
        const float* tb = topic + b * TOPN;
        const float* t1 = Wt + (size_t)d * TOPN;
        const float* t2 = Wt2 + (size_t)d * TOPN;
#pragma unroll 2
        for (int t = 0; t < TOPN; ++t) {
            float x = tb[t];
            a1 = fmaf(x, t1[t], a1);
            a2 = fmaf(x, t2[t], a2);
        }
        bias1[idx] = a1;
        bias2[idx] = a2;
    }
}

// ============ doc score kernel (R3-verified MFMA kernel, 8 blocks) ============
__global__ __launch_bounds__(256) void score_mfma_kernel(
    const float* __restrict__ X,            // [nrows][512]
    const unsigned short* __restrict__ Wp,  // permuted bf16 weights
    const float* __restrict__ Wv,           // [512]
    const float* __restrict__ bias,         // [16][512]
    float* __restrict__ scores,             // [nrows]
    int bshift)                             // batch = row >> bshift
{
    __shared__ __align__(16) short lsA[256 * 8];
    __shared__ __align__(16) short lsB[2048 * 8];
    __shared__ float red[4][64];

    const int tid = threadIdx.x;
    const int lane = tid & 63;
    const int wid = tid >> 6;
    const int row0 = blockIdx.x * 64;

    const int srow = tid >> 2;
    const int kslot = tid & 3;
    const int sA = ((kslot >> 1) * 2 + (srow >> 5)) * 64 + (kslot & 1) * 32 + (srow & 31);
    const float4* xs4 = (const float4*)(X + (size_t)(row0 + srow) * DEC) + kslot * 2;

    const uint4* bsrc = (const uint4*)Wp + (size_t)wid * 512 + lane;

    f32x16 acc[8];
#pragma unroll
    for (int t = 0; t < 8; ++t)
        acc[t] = (f32x16){0.f,0.f,0.f,0.f, 0.f,0.f,0.f,0.f, 0.f,0.f,0.f,0.f, 0.f,0.f,0.f,0.f};

    const short8* lA = (const short8*)lsA;
    const short8* lB = (const short8*)lsB;

    for (int it = 0; it < 16; ++it) {
        uint4 bv[8];
#pragma unroll
        for (int i = 0; i < 8; ++i) bv[i] = bsrc[i * 64];
        bsrc += 2048;
#pragma unroll
        for (int i = 0; i < 8; ++i)
            *((uint4*)&lsB[((size_t)wid * 512 + i * 64 + lane) * 8]) = bv[i];

        float4 xv0 = xs4[0];
        float4 xv1 = xs4[1];
        xs4 += 8;
        union { unsigned int u[4]; short8 s; } xb;
        xb.u[0] = pkbf(xv0.x, xv0.y); xb.u[1] = pkbf(xv0.z, xv0.w);
        xb.u[2] = pkbf(xv1.x, xv1.y); xb.u[3] = pkbf(xv1.z, xv1.w);
        *((short8*)&lsA[sA * 8]) = xb.s;

        __syncthreads();

#pragma unroll
        for (int c = 0; c < 2; ++c) {
            short8 a0 = lA[(c * 2 + 0) * 64 + lane];
            short8 a1 = lA[(c * 2 + 1) * 64 + lane];
            short8 b0 = lB[c * 1024 + (wid * 4 + 0) * 64 + lane];
            short8 b1 = lB[c * 1024 + (wid * 4 + 1) * 64 + lane];
            short8 b2 = lB[c * 1024 + (wid * 4 + 2) * 64 + lane];
            short8 b3 = lB[c * 1024 + (wid * 4 + 3) * 64 + lane];
            acc[0] = __builtin_amdgcn_mfma_f32_32x32x16_bf16(a0, b0, acc[0], 0, 0, 0);
            acc[1] = __builtin_amdgcn_mfma_f32_32x32x16_bf16(a0, b1, acc[1], 0, 0, 0);
            acc[2] = __builtin_amdgcn_mfma_f32_32x32x16_bf16(a0, b2, acc[2], 0, 0, 0);
            acc[3] = __builtin_amdgcn_mfma_f32_32x32x16_bf16(a0, b3, acc[3], 0, 0, 0);
            acc[4] = __builtin_amdgcn_mfma_f32_32x32x16_bf16(a1, b0, acc[4], 0, 0, 0);
            acc[5] = __builtin_amdgcn_mfma_f32_32x32x16_bf16(a1, b1, acc[5], 0, 0, 0);
            acc[6] = __builtin_amdgcn_mfma_f32_32x32x16_bf16(a1, b2, acc[6], 0, 0, 0);
            acc[7] = __builtin_amdgcn_mfma_f32_32x32x16_bf16(a1, b3, acc[7], 0, 0, 0);
        }
        __syncthreads();
    }

    const int col = lane & 31;
    const int h = lane >> 5;
    float wv[4], bs[2][4];
    const int b0i = (row0) >> bshift;
    const int b1i = (row0 + 32) >> bshift;
#pragma unroll
    for (int nt = 0; nt < 4; ++nt) {
        int d = wid * 128 + nt * 32 + col;
        wv[nt] = Wv[d];
        bs[0][nt] = bias[b0i * DEC + d];
        bs[1][nt] = bias[b1i * DEC + d];
    }

#pragma unroll
    for (int mt = 0; mt < 2; ++mt) {
#pragma unroll
        for (int r = 0; r < 16; ++r) {
            float p = 0.f;
#pragma unroll
            for (int nt = 0; nt < 4; ++nt) {
                float x = acc[mt * 4 + nt][r] + bs[mt][nt];
                p = fmaf(wv[nt], fast_tanh(x), p);
            }
            p += __shfl_xor(p, 16);
            p += __shfl_xor(p, 8);
            p += __shfl_xor(p, 4);
            p += __shfl_xor(p, 2);
            p += __shfl_xor(p, 1);
            if (col == mt * 16 + r) {
                int row_in = (r & 3) + 8 * (r >> 2) + 4 * h;
                red[wid][mt * 32 + row_in] = p;
            }
        }
    }
    __syncthreads();
    if (tid < 64)
        scores[row0 + tid] = red[0][tid] + red[1][tid] + red[2][tid] + red[3][tid];
}

// ============ doc softmax ============
__global__ __launch_bounds__(512) void doc_softmax_kernel(
    const float* __restrict__ doc_scores, const int* __restrict__ doc_mask,
    float* __restrict__ doc_attn)
{
    int tid = threadIdx.x;    // 512: b = tid>>5, q = tid&31
    float s = doc_scores[tid];
    if (doc_mask[tid] == 0) s = -INFINITY;
    float mx = s;
#pragma unroll
    for (int o = 1; o <= 16; o <<= 1) mx = fmaxf(mx, __shfl_xor(mx, o));
    float e = __expf(s - mx);
    float sum = e;
#pragma unroll
    for (int o = 1; o <= 16; o <<= 1) sum += __shfl_xor(sum, o);
    doc_attn[tid] = e / sum;
}

// ============ fused word kernel: scores (MFMA) + softmax + rescale + ctx ============
// Block = one (b,q): 128 word rows. 512 threads = 8 waves; wave w owns d in [w*64,(w+1)*64).
__global__ __launch_bounds__(512) void fused_word_kernel(
    const float* __restrict__ X,            // word_memory [65536][512]
    const unsigned short* __restrict__ Wp,  // permuted bf16 Wm
    const float* __restrict__ Wv,           // [512]
    const float* __restrict__ bias1,        // [16][512]
    const float* __restrict__ doc_attn,     // [512]
    const int* __restrict__ word_mask,      // [65536]
    float* __restrict__ rescaled_out,       // d_out + 8192
    float* __restrict__ ctx_part)           // [512][512]
{
    __shared__ __align__(16) short lsA[2 * 2048];   // 2 x 4KB double buffer (4 mt x 64 lanes x 8)
    __shared__ float red[8][128];
    __shared__ float sS[128];
    __shared__ float rmax2[2], rsum2[2];
    __shared__ __align__(16) float4 part[3 * 128];

    const int tid = threadIdx.x;
    const int lane = tid & 63;
    const int wid = tid >> 6;          // 0..7
    const int bq = blockIdx.x;         // 0..511
    const int r0 = bq * L2;            // first word row
    const int b = bq >> 5;

    // ---- A staging map: thread -> (row, kq) ----
    const int row = tid >> 2;          // 0..127
    const int kq = tid & 3;            // float4 index within 16-k chunk
    const int mt_s = row >> 5;
    const int rl_s = row & 31;
    const int k8_s = kq >> 1;
    const int q4 = (kq & 1) * 4;       // short offset within slot
    const int slot_s = mt_s * 64 + k8_s * 32 + rl_s;
    const float4* xs = (const float4*)(X + (size_t)(r0 + row) * DEC) + kq;

    const uint4* Bp = (const uint4*)Wp;
    const int boff = wid * 128 + lane;

    f32x16 acc[8];   // [mt*2 + nt]
#pragma unroll
    for (int t = 0; t < 8; ++t)
        acc[t] = (f32x16){0.f,0.f,0.f,0.f, 0.f,0.f,0.f,0.f, 0.f,0.f,0.f,0.f, 0.f,0.f,0.f,0.f};

    const short8* lA = (const short8*)lsA;

    // preload chunk 0
    float4 va = xs[0];
    uint4 ub0 = Bp[boff];
    uint4 ub1 = Bp[boff + 64];

    for (int c = 0; c < 32; ++c) {
        const int p = c & 1;
        // write A chunk c into buffer p (waits on va's vmcnt automatically)
        uint2 wv2;
        wv2.x = pkbf(va.x, va.y);
        wv2.y = pkbf(va.z, va.w);
        *(uint2*)&lsA[(p * 256 + slot_s) * 8 + q4] = wv2;
        __syncthreads();

        // prefetch A + B for chunk c+1 (wraps harmlessly on last iter)
        const int c2 = (c + 1) & 31;
        float4 vnext = xs[c2 * 4];
        uint4 nb0 = Bp[c2 * 1024 + boff];
        uint4 nb1 = Bp[c2 * 1024 + boff + 64];

        short8 a0 = lA[p * 256 + 0 * 64 + lane];
        short8 a1 = lA[p * 256 + 1 * 64 + lane];
        short8 a2 = lA[p * 256 + 2 * 64 + lane];
        short8 a3 = lA[p * 256 + 3 * 64 + lane];
        union { uint4 u; short8 s; } cb0{ub0}, cb1{ub1};
        acc[0] = __builtin_amdgcn_mfma_f32_32x32x16_bf16(a0, cb0.s, acc[0], 0, 0, 0);
        acc[1] = __builtin_amdgcn_mfma_f32_32x32x16_bf16(a0, cb1.s, acc[1], 0, 0, 0);
        acc[2] = __builtin_amdgcn_mfma_f32_32x32x16_bf16(a1, cb0.s, acc[2], 0, 0, 0);
        acc[3] = __builtin_amdgcn_mfma_f32_32x32x16_bf16(a1, cb1.s, acc[3], 0, 0, 0);
        acc[4] = __builtin_amdgcn_mfma_f32_32x32x16_bf16(a2, cb0.s, acc[4], 0, 0, 0);
        acc[5] = __builtin_amdgcn_mfma_f32_32x32x16_bf16(a2, cb1.s, acc[5], 0, 0, 0);
        acc[6] = __builtin_amdgcn_mfma_f32_32x32x16_bf16(a3, cb0.s, acc[6], 0, 0, 0);
        acc[7] = __builtin_amdgcn_mfma_f32_32x32x16_bf16(a3, cb1.s, acc[7], 0, 0, 0);

        va = vnext; ub0 = nb0; ub1 = nb1;
    }

    // ---- epilogue: tanh + Wv partial over this wave's 64 d ----
    // C/D layout (32x32, HW-verified): col = lane&31, row_in = (r&3) + 8*(r>>2) + 4*(lane>>5)
    const int col = lane & 31;
    const int h = lane >> 5;
    float wv0, wv1, bs0, bs1;
    {
        int d0 = wid * 64 + col;
        int d1 = wid * 64 + 32 + col;
        wv0 = Wv[d0]; wv1 = Wv[d1];
        bs0 = bias1[b * DEC + d0]; bs1 = bias1[b * DEC + d1];
    }
#pragma unroll
    for (int mt = 0; mt < 4; ++mt) {
#pragma unroll
        for (int r = 0; r < 16; ++r) {
            float p = fmaf(wv0, fast_tanh(acc[mt * 2 + 0][r] + bs0),
                           wv1 * fast_tanh(acc[mt * 2 + 1][r] + bs1));
            p += __shfl_xor(p, 16);
            p += __shfl_xor(p, 8);
            p += __shfl_xor(p, 4);
            p += __shfl_xor(p, 2);
            p += __shfl_xor(p, 1);
            if (col == r) {
                int row_in = (r & 3) + 8 * (r >> 2) + 4 * h;
                red[wid][mt * 32 + row_in] = p;
            }
        }
    }
    __syncthreads();

    // ---- block softmax over 128 words (threads 0..127 = waves 0,1) ----
    float e = 0.f, sv = 0.f;
    if (tid < 128) {
        sv = red[0][tid] + red[1][tid] + red[2][tid] + red[3][tid]
           + red[4][tid] + red[5][tid] + red[6][tid] + red[7][tid];
        if (word_mask[r0 + tid] == 0) sv = -INFINITY;
        float mx = sv;
#pragma unroll
        for (int o = 1; o <= 32; o <<= 1) mx = fmaxf(mx, __shfl_xor(mx, o));
        if (lane == 0) rmax2[wid] = mx;
    }
    __syncthreads();
    if (tid < 128) {
        float mx = fmaxf(rmax2[0], rmax2[1]);
        e = __expf(sv - mx);
        float sum = e;
#pragma unroll
        for (int o = 1; o <= 32; o <<= 1) sum += __shfl_xor(sum, o);
        if (lane == 0) rsum2[wid] = sum;
    }
    __syncthreads();
    if (tid < 128) {
        float sum = rsum2[0] + rsum2[1];
        float resc = doc_attn[bq] * (e / sum);
        sS[tid] = resc;
        rescaled_out[r0 + tid] = resc;
    }
    __syncthreads();

    // ---- context partial (fp32 X re-read, L2/L3-hot) ----
    const int hh = tid >> 7;          // 0..3: w-group of 32
    const int m4 = tid & 127;         // float4 index in m
    const float4* Xr = (const float4*)X + (size_t)r0 * 128 + (size_t)hh * 32 * 128 + m4;
    float4 a = {0.f, 0.f, 0.f, 0.f};
#pragma unroll 8
    for (int i = 0; i < 32; ++i) {
        float rr = sS[hh * 32 + i];
        float4 v = Xr[(size_t)i * 128];
        a.x = fmaf(rr, v.x, a.x);
        a.y = fmaf(rr, v.y, a.y);
        a.z = fmaf(rr, v.z, a.z);
        a.w = fmaf(rr, v.w, a.w);
    }
    if (hh) part[(hh - 1) * 128 + m4] = a;
    __syncthreads();
    if (hh == 0) {
        float4 p0 = part[m4], p1 = part[128 + m4], p2 = part[256 + m4];
        a.x += p0.x + p1.x + p2.x;
        a.y += p0.y + p1.y + p2.y;
        a.z += p0.z + p1.z + p2.z;
        a.w += p0.w + p1.w + p2.w;
        *(float4*)(ctx_part + (size_t)bq * MEM + m4 * 4) = a;
    }
}

// ============ reduce context over q ============
__global__ __launch_bounds__(256) void ctx_reduce_kernel(
    const float* __restrict__ ctx_part,   // [512][512]
    float* __restrict__ ctx_out)          // [16][512]
{
    int idx = blockIdx.x * 256 + threadIdx.x;   // 8192
    int b = idx >> 9, m = idx & 511;
    float s = 0.f;
#pragma unroll
    for (int q = 0; q < L1; ++q)
        s += ctx_part[(size_t)(b * L1 + q) * MEM + m];
    ctx_out[idx] = s;
}

extern "C" void kernel_launch(void* const* d_in, const int* in_sizes, int n_in,
                              void* d_out, int out_size, void* d_ws, size_t ws_size,
                              hipStream_t stream) {
    const float* decoder_state = (const float*)d_in[0];
    const float* doc_memory    = (const float*)d_in[1];
    const float* word_memory   = (const float*)d_in[2];
    const float* topic_dist    = (const float*)d_in[3];
    const int*   doc_mask      = (const int*)d_in[4];
    const int*   word_mask     = (const int*)d_in[5];
    const float* Wv  = (const float*)d_in[6];
    const float* Wd  = (const float*)d_in[7];
    const float* Wt  = (const float*)d_in[8];
    const float* Wm  = (const float*)d_in[9];
    const float* Wv2 = (const float*)d_in[10];
    const float* Wd2 = (const float*)d_in[11];
    const float* Wt2 = (const float*)d_in[12];
    const float* Wm2 = (const float*)d_in[13];

    float* ws = (float*)d_ws;
    unsigned short* Wp  = (unsigned short*)(ws + WS_WP);
    unsigned short* Wp2 = (unsigned short*)(ws + WS_WP2);
    float* bias1       = ws + WS_BIAS1;
    float* bias2       = ws + WS_BIAS2;
    float* doc_scores  = ws + WS_DOCSC;
    float* doc_attn    = ws + WS_DOCAT;
    float* ctx_part    = ws + WS_CTXP;

    float* ctx_out      = (float*)d_out;                 // [16][512]
    float* rescaled_out = (float*)d_out + BATCH * MEM;   // [16][32][128]

    setup_kernel<<<160, 256, 0, stream>>>(Wm, Wm2, Wp, Wp2,
                                          decoder_state, topic_dist,
                                          Wd, Wt, Wd2, Wt2, bias1, bias2);
    score_mfma_kernel<<<NBQ / 64, 256, 0, stream>>>(doc_memory, Wp2, Wv2, bias2, doc_scores, 5);
    doc_softmax_kernel<<<1, 512, 0, stream>>>(doc_scores, doc_mask, doc_attn);
    fused_word_kernel<<<NBQ, 512, 0, stream>>>(word_memory, Wp, Wv, bias1,
                                               doc_attn, word_mask, rescaled_out, ctx_part);
    ctx_reduce_kernel<<<32, 256, 0, stream>>>(ctx_part, ctx_out);
}

// Round 5
// 351.681 us; speedup vs baseline: 1.9648x; 1.0472x over previous
//
#include <hip/hip_runtime.h>
#include <hip/hip_bf16.h>
#include <math.h>

// Problem constants
#define BATCH 16
#define L1 32
#define L2 128
#define DEC 512
#define MEM 512
#define TOPN 50
#define NROWS (BATCH * L1 * L2)   // 65536 word rows
#define NBQ (BATCH * L1)          // 512 (b,q) rows

typedef short short8 __attribute__((ext_vector_type(8)));
typedef float f32x16 __attribute__((ext_vector_type(16)));

// ---------------- ws layout (floats) ----------------
#define WS_WP     0          // perm bf16 Wm : 32768 slots x 16B = floats [0,131072)
#define WS_WP2    131072     // perm bf16 Wm2
#define WS_BIAS1  262144
#define WS_BIAS2  270336
#define WS_DOCSC  278528     // doc scores [512] -> end 279040 (~1.07 MB total)

// packed pair via v_cvt_pk_bf16_f32
__device__ __forceinline__ unsigned int pkbf(float a, float b) {
    __hip_bfloat162 h = __float22bfloat162_rn(float2{a, b});
    union { __hip_bfloat162 h; unsigned int u; } c{h};
    return c.u;
}

__device__ __forceinline__ float fast_tanh(float x) {
    return 1.f - 2.f / (__expf(2.f * x) + 1.f);
}

// ============ kernel 0 (merged setup): permute Wm/Wm2 + bias1/bias2 + zero ctx ============
// permute slot s (16B) holds Wm[d][k..k+7] bf16: s = C*1024 + nt*64 + k8*32 + n
//   d = nt*32+n ; k = C*16 + k8*8      (layout HW-verified in R3)
__global__ __launch_bounds__(256) void setup_kernel(
    const float* __restrict__ Wm, const float* __restrict__ Wm2,
    unsigned short* __restrict__ Wp, unsigned short* __restrict__ Wp2,
    const float* __restrict__ dec, const float* __restrict__ topic,
    const float* __restrict__ Wd, const float* __restrict__ Wt,
    const float* __restrict__ Wd2, const float* __restrict__ Wt2,
    float* __restrict__ bias1, float* __restrict__ bias2,
    float* __restrict__ ctx_out)
{
    if (blockIdx.x < 128) {
        int s = blockIdx.x * 256 + threadIdx.x;     // 0..32767
        int C = s >> 10;
        int u = s & 1023;
        int nt = u >> 6, k8 = (u >> 5) & 1, n_in = u & 31;
        int d = nt * 32 + n_in;
        int k = C * 16 + k8 * 8;

        const float* src = Wm + (size_t)d * DEC + k;
        uint4 v;
        v.x = pkbf(src[0], src[1]); v.y = pkbf(src[2], src[3]);
        v.z = pkbf(src[4], src[5]); v.w = pkbf(src[6], src[7]);
        ((uint4*)Wp)[s] = v;

        const float* src2 = Wm2 + (size_t)d * DEC + k;
        uint4 w;
        w.x = pkbf(src2[0], src2[1]); w.y = pkbf(src2[2], src2[3]);
        w.z = pkbf(src2[4], src2[5]); w.w = pkbf(src2[6], src2[7]);
        ((uint4*)Wp2)[s] = w;
    } else if (blockIdx.x < 160) {
        int idx = (blockIdx.x - 128) * 256 + threadIdx.x;   // 8192
        int b = idx >> 9, d = idx & 511;
        float a1 = 0.f, a2 = 0.f;
        const float* db = dec + b * DEC;
        const float* w1 = Wd + (size_t)d * DEC;
        const float* w2 = Wd2 + (size_t)d * DEC;
#pragma unroll 4
        for (int k = 0; k < DEC; ++k) {
            float x = db[k];
            a1 = fmaf(x, w1[k], a1);
            a2 = fmaf(x, w2[k], a2);
        }
        const float* tb = topic + b * TOPN;
        const float* t1 = Wt + (size_t)d * TOPN;
        const float* t2 = Wt2 + (size_t)d * TOPN;
#pragma unroll 2
        for (int t = 0; t < TOPN; ++t) {
            float x = tb[t];
            a1 = fmaf(x, t1[t], a1);
            a2 = fmaf(x, t2[t], a2);
        }
        bias1[idx] = a1;
        bias2[idx] = a2;
    } else {
        // zero ctx accumulator region of d_out (8192 floats)
        int i = (blockIdx.x - 160) * 256 + threadIdx.x;   // 0..1023
        float4 z = {0.f, 0.f, 0.f, 0.f};
        ((float4*)ctx_out)[i * 2] = z;
        ((float4*)ctx_out)[i * 2 + 1] = z;
    }
}

// ============ doc score kernel (R3-verified MFMA kernel, 8 blocks) ============
__global__ __launch_bounds__(256) void score_mfma_kernel(
    const float* __restrict__ X,            // [nrows][512]
    const unsigned short* __restrict__ Wp,  // permuted bf16 weights
    const float* __restrict__ Wv,           // [512]
    const float* __restrict__ bias,         // [16][512]
    float* __restrict__ scores,             // [nrows]
    int bshift)                             // batch = row >> bshift
{
    __shared__ __align__(16) short lsA[256 * 8];
    __shared__ __align__(16) short lsB[2048 * 8];
    __shared__ float red[4][64];

    const int tid = threadIdx.x;
    const int lane = tid & 63;
    const int wid = tid >> 6;
    const int row0 = blockIdx.x * 64;

    const int srow = tid >> 2;
    const int kslot = tid & 3;
    const int sA = ((kslot >> 1) * 2 + (srow >> 5)) * 64 + (kslot & 1) * 32 + (srow & 31);
    const float4* xs4 = (const float4*)(X + (size_t)(row0 + srow) * DEC) + kslot * 2;

    const uint4* bsrc = (const uint4*)Wp + (size_t)wid * 512 + lane;

    f32x16 acc[8];
#pragma unroll
    for (int t = 0; t < 8; ++t)
        acc[t] = (f32x16){0.f,0.f,0.f,0.f, 0.f,0.f,0.f,0.f, 0.f,0.f,0.f,0.f, 0.f,0.f,0.f,0.f};

    const short8* lA = (const short8*)lsA;
    const short8* lB = (const short8*)lsB;

    for (int it = 0; it < 16; ++it) {
        uint4 bv[8];
#pragma unroll
        for (int i = 0; i < 8; ++i) bv[i] = bsrc[i * 64];
        bsrc += 2048;
#pragma unroll
        for (int i = 0; i < 8; ++i)
            *((uint4*)&lsB[((size_t)wid * 512 + i * 64 + lane) * 8]) = bv[i];

        float4 xv0 = xs4[0];
        float4 xv1 = xs4[1];
        xs4 += 8;
        union { unsigned int u[4]; short8 s; } xb;
        xb.u[0] = pkbf(xv0.x, xv0.y); xb.u[1] = pkbf(xv0.z, xv0.w);
        xb.u[2] = pkbf(xv1.x, xv1.y); xb.u[3] = pkbf(xv1.z, xv1.w);
        *((short8*)&lsA[sA * 8]) = xb.s;

        __syncthreads();

#pragma unroll
        for (int c = 0; c < 2; ++c) {
            short8 a0 = lA[(c * 2 + 0) * 64 + lane];
            short8 a1 = lA[(c * 2 + 1) * 64 + lane];
            short8 b0 = lB[c * 1024 + (wid * 4 + 0) * 64 + lane];
            short8 b1 = lB[c * 1024 + (wid * 4 + 1) * 64 + lane];
            short8 b2 = lB[c * 1024 + (wid * 4 + 2) * 64 + lane];
            short8 b3 = lB[c * 1024 + (wid * 4 + 3) * 64 + lane];
            acc[0] = __builtin_amdgcn_mfma_f32_32x32x16_bf16(a0, b0, acc[0], 0, 0, 0);
            acc[1] = __builtin_amdgcn_mfma_f32_32x32x16_bf16(a0, b1, acc[1], 0, 0, 0);
            acc[2] = __builtin_amdgcn_mfma_f32_32x32x16_bf16(a0, b2, acc[2], 0, 0, 0);
            acc[3] = __builtin_amdgcn_mfma_f32_32x32x16_bf16(a0, b3, acc[3], 0, 0, 0);
            acc[4] = __builtin_amdgcn_mfma_f32_32x32x16_bf16(a1, b0, acc[4], 0, 0, 0);
            acc[5] = __builtin_amdgcn_mfma_f32_32x32x16_bf16(a1, b1, acc[5], 0, 0, 0);
            acc[6] = __builtin_amdgcn_mfma_f32_32x32x16_bf16(a1, b2, acc[6], 0, 0, 0);
            acc[7] = __builtin_amdgcn_mfma_f32_32x32x16_bf16(a1, b3, acc[7], 0, 0, 0);
        }
        __syncthreads();
    }

    const int col = lane & 31;
    const int h = lane >> 5;
    float wv[4], bs[2][4];
    const int b0i = (row0) >> bshift;
    const int b1i = (row0 + 32) >> bshift;
#pragma unroll
    for (int nt = 0; nt < 4; ++nt) {
        int d = wid * 128 + nt * 32 + col;
        wv[nt] = Wv[d];
        bs[0][nt] = bias[b0i * DEC + d];
        bs[1][nt] = bias[b1i * DEC + d];
    }

#pragma unroll
    for (int mt = 0; mt < 2; ++mt) {
#pragma unroll
        for (int r = 0; r < 16; ++r) {
            float p = 0.f;
#pragma unroll
            for (int nt = 0; nt < 4; ++nt) {
                float x = acc[mt * 4 + nt][r] + bs[mt][nt];
                p = fmaf(wv[nt], fast_tanh(x), p);
            }
            p += __shfl_xor(p, 16);
            p += __shfl_xor(p, 8);
            p += __shfl_xor(p, 4);
            p += __shfl_xor(p, 2);
            p += __shfl_xor(p, 1);
            if (col == mt * 16 + r) {
                int row_in = (r & 3) + 8 * (r >> 2) + 4 * h;
                red[wid][mt * 32 + row_in] = p;
            }
        }
    }
    __syncthreads();
    if (tid < 64)
        scores[row0 + tid] = red[0][tid] + red[1][tid] + red[2][tid] + red[3][tid];
}

// ============ fused word kernel: doc-softmax + scores (MFMA) + softmax + rescale + ctx ============
// Block = one (b,q): 128 word rows. 512 threads = 8 waves; wave w owns d in [w*64,(w+1)*64).
// A-prefetch 4 deep (HBM), B-prefetch 2 deep (L2). 1 block/CU (232 regs/wave), ILP covers latency.
__global__ __launch_bounds__(512) void fused_word_kernel(
    const float* __restrict__ X,            // word_memory [65536][512]
    const unsigned short* __restrict__ Wp,  // permuted bf16 Wm
    const float* __restrict__ Wv,           // [512]
    const float* __restrict__ bias1,        // [16][512]
    const float* __restrict__ doc_scores,   // [512]
    const int* __restrict__ doc_mask,       // [512]
    const int* __restrict__ word_mask,      // [65536]
    float* __restrict__ rescaled_out,       // d_out + 8192
    float* __restrict__ ctx_out)            // d_out [16][512], pre-zeroed, atomic
{
    __shared__ __align__(16) short lsA[2 * 2048];   // 2 x 4KB double buffer
    __shared__ float red[8][128];
    __shared__ float sS[128];
    __shared__ float rmax2[2], rsum2[2];
    __shared__ float s_dattn;
    __shared__ __align__(16) float4 part[3 * 128];

    const int tid = threadIdx.x;
    const int lane = tid & 63;
    const int wid = tid >> 6;          // 0..7
    const int bq = blockIdx.x;         // 0..511
    const int r0 = bq * L2;            // first word row
    const int b = bq >> 5;
    const int q = bq & 31;

    // ---- doc softmax for this block's (b,q): one scalar ----
    if (tid < 32) {
        int di = b * 32 + tid;
        float dsv = doc_scores[di];
        if (doc_mask[di] == 0) dsv = -INFINITY;
        float mx = dsv;
#pragma unroll
        for (int o = 1; o <= 16; o <<= 1) mx = fmaxf(mx, __shfl_xor(mx, o));
        float e = __expf(dsv - mx);
        float sum = e;
#pragma unroll
        for (int o = 1; o <= 16; o <<= 1) sum += __shfl_xor(sum, o);
        if (tid == q) s_dattn = e / sum;
    }

    // ---- A staging map: thread -> (row, kq) ----
    const int row = tid >> 2;          // 0..127
    const int kq = tid & 3;            // float4 index within 16-k chunk
    const int mt_s = row >> 5;
    const int rl_s = row & 31;
    const int k8_s = kq >> 1;
    const int q4 = (kq & 1) * 4;       // short offset within slot
    const int slot_s = mt_s * 64 + k8_s * 32 + rl_s;
    const float4* xs = (const float4*)(X + (size_t)(r0 + row) * DEC) + kq;

    const uint4* Bp = (const uint4*)Wp;
    const int boff = wid * 128 + lane;

    f32x16 acc[8];   // [mt*2 + nt]
#pragma unroll
    for (int t = 0; t < 8; ++t)
        acc[t] = (f32x16){0.f,0.f,0.f,0.f, 0.f,0.f,0.f,0.f, 0.f,0.f,0.f,0.f, 0.f,0.f,0.f,0.f};

    const short8* lA = (const short8*)lsA;

    // ---- deep prefetch: A chunks 0..3, B chunks 0..1 ----
    float4 va[4];
#pragma unroll
    for (int i = 0; i < 4; ++i) va[i] = xs[i * 4];
    uint4 ub0[2], ub1[2];
#pragma unroll
    for (int i = 0; i < 2; ++i) {
        ub0[i] = Bp[i * 1024 + boff];
        ub1[i] = Bp[i * 1024 + boff + 64];
    }

#pragma unroll
    for (int c = 0; c < 32; ++c) {
        const int p = c & 1;
        const int ia = c & 3;
        // write A chunk c into buffer p (waits vmcnt for va[ia], issued 4 iters ago)
        uint2 w2;
        w2.x = pkbf(va[ia].x, va[ia].y);
        w2.y = pkbf(va[ia].z, va[ia].w);
        *(uint2*)&lsA[(p * 256 + slot_s) * 8 + q4] = w2;
        __syncthreads();

        // refill prefetch: A 4 ahead, B 2 ahead (wrap -> dead-but-valid loads)
        va[ia] = xs[((c + 4) & 31) * 4];
        uint4 nb0 = Bp[((c + 2) & 31) * 1024 + boff];
        uint4 nb1 = Bp[((c + 2) & 31) * 1024 + boff + 64];

        short8 a0 = lA[p * 256 + 0 * 64 + lane];
        short8 a1 = lA[p * 256 + 1 * 64 + lane];
        short8 a2 = lA[p * 256 + 2 * 64 + lane];
        short8 a3 = lA[p * 256 + 3 * 64 + lane];
        union { uint4 u; short8 s; } cb0{ub0[p]}, cb1{ub1[p]};
        acc[0] = __builtin_amdgcn_mfma_f32_32x32x16_bf16(a0, cb0.s, acc[0], 0, 0, 0);
        acc[1] = __builtin_amdgcn_mfma_f32_32x32x16_bf16(a0, cb1.s, acc[1], 0, 0, 0);
        acc[2] = __builtin_amdgcn_mfma_f32_32x32x16_bf16(a1, cb0.s, acc[2], 0, 0, 0);
        acc[3] = __builtin_amdgcn_mfma_f32_32x32x16_bf16(a1, cb1.s, acc[3], 0, 0, 0);
        acc[4] = __builtin_amdgcn_mfma_f32_32x32x16_bf16(a2, cb0.s, acc[4], 0, 0, 0);
        acc[5] = __builtin_amdgcn_mfma_f32_32x32x16_bf16(a2, cb1.s, acc[5], 0, 0, 0);
        acc[6] = __builtin_amdgcn_mfma_f32_32x32x16_bf16(a3, cb0.s, acc[6], 0, 0, 0);
        acc[7] = __builtin_amdgcn_mfma_f32_32x32x16_bf16(a3, cb1.s, acc[7], 0, 0, 0);

        ub0[p] = nb0; ub1[p] = nb1;
    }

    // ---- epilogue: tanh + Wv partial over this wave's 64 d ----
    // C/D layout (32x32, HW-verified): col = lane&31, row_in = (r&3) + 8*(r>>2) + 4*(lane>>5)
    const int col = lane & 31;
    const int h = lane >> 5;
    float wv0, wv1, bs0, bs1;
    {
        int d0 = wid * 64 + col;
        int d1 = wid * 64 + 32 + col;
        wv0 = Wv[d0]; wv1 = Wv[d1];
        bs0 = bias1[b * DEC + d0]; bs1 = bias1[b * DEC + d1];
    }
#pragma unroll
    for (int mt = 0; mt < 4; ++mt) {
#pragma unroll
        for (int r = 0; r < 16; ++r) {
            float p = fmaf(wv0, fast_tanh(acc[mt * 2 + 0][r] + bs0),
                           wv1 * fast_tanh(acc[mt * 2 + 1][r] + bs1));
            p += __shfl_xor(p, 16);
            p += __shfl_xor(p, 8);
            p += __shfl_xor(p, 4);
            p += __shfl_xor(p, 2);
            p += __shfl_xor(p, 1);
            if (col == r) {
                int row_in = (r & 3) + 8 * (r >> 2) + 4 * h;
                red[wid][mt * 32 + row_in] = p;
            }
        }
    }
    __syncthreads();

    // ---- block softmax over 128 words (threads 0..127) ----
    float e = 0.f, sv = 0.f;
    if (tid < 128) {
        sv = red[0][tid] + red[1][tid] + red[2][tid] + red[3][tid]
           + red[4][tid] + red[5][tid] + red[6][tid] + red[7][tid];
        if (word_mask[r0 + tid] == 0) sv = -INFINITY;
        float mx = sv;
#pragma unroll
        for (int o = 1; o <= 32; o <<= 1) mx = fmaxf(mx, __shfl_xor(mx, o));
        if (lane == 0) rmax2[wid] = mx;
    }
    __syncthreads();
    if (tid < 128) {
        float mx = fmaxf(rmax2[0], rmax2[1]);
        e = __expf(sv - mx);
        float sum = e;
#pragma unroll
        for (int o = 1; o <= 32; o <<= 1) sum += __shfl_xor(sum, o);
        if (lane == 0) rsum2[wid] = sum;
    }
    __syncthreads();
    if (tid < 128) {
        float sum = rsum2[0] + rsum2[1];
        float resc = s_dattn * (e / sum);
        sS[tid] = resc;
        rescaled_out[r0 + tid] = resc;
    }
    __syncthreads();

    // ---- context partial (fp32 X re-read, L2-hot) + atomic accumulate ----
    const int hh = tid >> 7;          // 0..3: w-group of 32
    const int m4 = tid & 127;         // float4 index in m
    const float4* Xr = (const float4*)X + (size_t)r0 * 128 + (size_t)hh * 32 * 128 + m4;
    float4 a = {0.f, 0.f, 0.f, 0.f};
#pragma unroll 8
    for (int i = 0; i < 32; ++i) {
        float rr = sS[hh * 32 + i];
        float4 v = Xr[(size_t)i * 128];
        a.x = fmaf(rr, v.x, a.x);
        a.y = fmaf(rr, v.y, a.y);
        a.z = fmaf(rr, v.z, a.z);
        a.w = fmaf(rr, v.w, a.w);
    }
    if (hh) part[(hh - 1) * 128 + m4] = a;
    __syncthreads();
    if (hh == 0) {
        float4 p0 = part[m4], p1 = part[128 + m4], p2 = part[256 + m4];
        a.x += p0.x + p1.x + p2.x;
        a.y += p0.y + p1.y + p2.y;
        a.z += p0.z + p1.z + p2.z;
        a.w += p0.w + p1.w + p2.w;
        float* dst = ctx_out + (size_t)b * MEM + m4 * 4;
        atomicAdd(dst + 0, a.x);
        atomicAdd(dst + 1, a.y);
        atomicAdd(dst + 2, a.z);
        atomicAdd(dst + 3, a.w);
    }
}

extern "C" void kernel_launch(void* const* d_in, const int* in_sizes, int n_in,
                              void* d_out, int out_size, void* d_ws, size_t ws_size,
                              hipStream_t stream) {
    const float* decoder_state = (const float*)d_in[0];
    const float* doc_memory    = (const float*)d_in[1];
    const float* word_memory   = (const float*)d_in[2];
    const float* topic_dist    = (const float*)d_in[3];
    const int*   doc_mask      = (const int*)d_in[4];
    const int*   word_mask     = (const int*)d_in[5];
    const float* Wv  = (const float*)d_in[6];
    const float* Wd  = (const float*)d_in[7];
    const float* Wt  = (const float*)d_in[8];
    const float* Wm  = (const float*)d_in[9];
    const float* Wv2 = (const float*)d_in[10];
    const float* Wd2 = (const float*)d_in[11];
    const float* Wt2 = (const float*)d_in[12];
    const float* Wm2 = (const float*)d_in[13];

    float* ws = (float*)d_ws;
    unsigned short* Wp  = (unsigned short*)(ws + WS_WP);
    unsigned short* Wp2 = (unsigned short*)(ws + WS_WP2);
    float* bias1       = ws + WS_BIAS1;
    float* bias2       = ws + WS_BIAS2;
    float* doc_scores  = ws + WS_DOCSC;

    float* ctx_out      = (float*)d_out;                 // [16][512]
    float* rescaled_out = (float*)d_out + BATCH * MEM;   // [16][32][128]

    setup_kernel<<<164, 256, 0, stream>>>(Wm, Wm2, Wp, Wp2,
                                          decoder_state, topic_dist,
                                          Wd, Wt, Wd2, Wt2, bias1, bias2, ctx_out);
    score_mfma_kernel<<<NBQ / 64, 256, 0, stream>>>(doc_memory, Wp2, Wv2, bias2, doc_scores, 5);
    fused_word_kernel<<<NBQ, 512, 0, stream>>>(word_memory, Wp, Wv, bias1,
                                               doc_scores, doc_mask, word_mask,
                                               rescaled_out, ctx_out);
}